// Round 1
// baseline (580.178 us; speedup 1.0000x reference)
//
#include <hip/hip_runtime.h>
#include <math.h>

#define B_ 4
#define T_ 128
#define V_ 50257
#define LSRC_ 512
#define D_ 512
#define NROWS 512           // B*T
#define GAMMA2_ 0.1f

#define BK 32
#define KC 1600             // k per split chunk (multiple of 32)
#define SPLITK 32           // 32*1600 = 51200 >= 50257
#define LDA 40              // As row stride in shorts (32 + 8 pad, keeps 16B align)
#define LDB 40              // Bs row stride in shorts

typedef __attribute__((ext_vector_type(8))) short s8v;     // 8 bf16 (4 VGPRs)
typedef __attribute__((ext_vector_type(4))) float f4v;     // MFMA C/D

// ws layout (floats): [0]=nll_sum [1]=valid_cnt [2]=cov_sum [3]=declen_sum [4]=ot_sum
// [256 ..] pred[512*512]
#define WS_PRED_OFF 256

__device__ inline unsigned short f2bf(float f) {
    // round-to-nearest-even; inputs here are finite and well-scaled
    unsigned int u = __float_as_uint(f);
    u += 0x7fffu + ((u >> 16) & 1u);
    return (unsigned short)(u >> 16);
}

__device__ inline float wave_reduce(float v) {
    #pragma unroll
    for (int o = 32; o > 0; o >>= 1) v += __shfl_down(v, o, 64);
    return v;
}

// ---------------- misc: nll, coverage, dec_len sums ----------------
__global__ void misc_kernel(const float* __restrict__ output_mle,
                            const float* __restrict__ attn,
                            const float* __restrict__ cover,
                            const int* __restrict__ trg,
                            const int* __restrict__ dec_mask,
                            const int* __restrict__ dec_len,
                            float* __restrict__ acc) {
    int bid = blockIdx.x;
    if (bid < 255) {
        float s = 0.f;
        const int total = B_ * LSRC_ * T_;          // 262144
        for (int idx = bid * 256 + threadIdx.x; idx < total; idx += 255 * 256) {
            int b = idx >> 16;                      // / (LSRC*T) = / 65536
            int t = idx & (T_ - 1);                 // rem % T
            float m = fminf(attn[idx], cover[idx]);
            if (dec_mask[b * T_ + t]) m = 0.f;
            s += m;
        }
        s = wave_reduce(s);
        if ((threadIdx.x & 63) == 0) atomicAdd(&acc[2], s);
    } else {
        float lp = 0.f, cnt = 0.f;
        for (int i = threadIdx.x; i < NROWS; i += 256) {
            int tg = trg[i];
            if (tg != 0) {
                lp += __logf(output_mle[(size_t)i * V_ + tg]);
                cnt += 1.f;
            }
        }
        lp = wave_reduce(lp); cnt = wave_reduce(cnt);
        if ((threadIdx.x & 63) == 0) { atomicAdd(&acc[0], lp); atomicAdd(&acc[1], cnt); }
        if (threadIdx.x < B_) atomicAdd(&acc[3], (float)dec_len[threadIdx.x]);
    }
}

// ---------------- GEMM: pred += exp(X) * W  (split-K, bf16 MFMA) ----------------
// X: [512][V] fp32 (output_mle), W: [V][512] fp32, pred: [512][512] fp32 (atomic accum)
__launch_bounds__(256)
__global__ void gemm_kernel(const float* __restrict__ X,
                            const float* __restrict__ W,
                            float* __restrict__ pred) {
    __shared__ __align__(16) short As[128 * LDA];
    __shared__ __align__(16) short Bs[128 * LDB];

    const int bx   = blockIdx.x;
    const int tile = bx & 15;
    const int s    = bx >> 4;
    const int i0   = (tile & 3) * 128;    // row block (B*T rows)
    const int d0   = (tile >> 2) * 128;   // col block (D)
    const int ks   = s * KC;
    const int ke   = min(ks + KC, V_);

    const int tid  = threadIdx.x;
    const int lane = tid & 63;
    const int wave = tid >> 6;
    const int wm   = (wave & 1) * 64;
    const int wn   = (wave >> 1) * 64;
    const int l15  = lane & 15;
    const int l4   = lane >> 4;

    f4v acc[4][4];
    #pragma unroll
    for (int a = 0; a < 4; a++)
        #pragma unroll
        for (int b = 0; b < 4; b++) acc[a][b] = (f4v)0.f;

    for (int k0 = ks; k0 < ke; k0 += BK) {
        // ---- stage A: As[m][k] = bf16(exp(X[i0+m][k0+k])), m<128, k<32
        #pragma unroll
        for (int p = 0; p < 8; p++) {
            int m  = p * 16 + (tid >> 4);
            int k2 = (tid & 15) * 2;
            int gk = k0 + k2;
            const float* xp = X + (size_t)(i0 + m) * V_ + gk;
            float e0 = (gk     < ke) ? __expf(xp[0]) : 0.f;
            float e1 = (gk + 1 < ke) ? __expf(xp[1]) : 0.f;
            unsigned int u = (unsigned int)f2bf(e0) | ((unsigned int)f2bf(e1) << 16);
            *(unsigned int*)&As[m * LDA + k2] = u;
        }
        // ---- stage B (transposed): Bs[n][k] = bf16(W[k0+k][d0+n]), n<128, k<32
        #pragma unroll
        for (int p = 0; p < 2; p++) {
            int n = tid & 127;
            int o = (tid >> 7) + p * 2;   // k-octet 0..3
            s8v bs;
            #pragma unroll
            for (int j = 0; j < 8; j++) {
                int gk = k0 + o * 8 + j;
                float v = (gk < ke) ? W[(size_t)gk * D_ + d0 + n] : 0.f;
                bs[j] = (short)f2bf(v);
            }
            *(s8v*)&Bs[n * LDB + o * 8] = bs;
        }
        __syncthreads();

        // ---- MFMA: each wave does 64x64 via 4x4 fragments of 16x16x32
        s8v af[4], bf[4];
        #pragma unroll
        for (int mi = 0; mi < 4; mi++)
            af[mi] = *(const s8v*)&As[(wm + mi * 16 + l15) * LDA + l4 * 8];
        #pragma unroll
        for (int ni = 0; ni < 4; ni++)
            bf[ni] = *(const s8v*)&Bs[(wn + ni * 16 + l15) * LDB + l4 * 8];
        #pragma unroll
        for (int mi = 0; mi < 4; mi++)
            #pragma unroll
            for (int ni = 0; ni < 4; ni++)
                acc[mi][ni] = __builtin_amdgcn_mfma_f32_16x16x32_bf16(
                    af[mi], bf[ni], acc[mi][ni], 0, 0, 0);
        __syncthreads();
    }

    // ---- epilogue: C/D layout col=lane&15, row=(lane>>4)*4+r
    #pragma unroll
    for (int mi = 0; mi < 4; mi++) {
        #pragma unroll
        for (int ni = 0; ni < 4; ni++) {
            int col = d0 + wn + ni * 16 + l15;
            #pragma unroll
            for (int r = 0; r < 4; r++) {
                int row = i0 + wm + mi * 16 + l4 * 4 + r;
                atomicAdd(&pred[row * D_ + col], acc[mi][ni][r]);
            }
        }
    }
}

// ---------------- ot: mean_i cos(pred_i, W[trg_i]) ----------------
__global__ void ot_kernel(const float* __restrict__ pred,
                          const float* __restrict__ W,
                          const int* __restrict__ trg,
                          float* __restrict__ acc) {
    int i = blockIdx.x;
    const float* p = pred + (size_t)i * D_;
    const float* t = W + (size_t)trg[i] * D_;
    float dot = 0.f, nn = 0.f, tt = 0.f;
    for (int d = threadIdx.x; d < D_; d += 256) {
        float pv = p[d], tv = t[d];
        dot += pv * tv; nn += pv * pv; tt += tv * tv;
    }
    __shared__ float red[3][4];
    dot = wave_reduce(dot); nn = wave_reduce(nn); tt = wave_reduce(tt);
    int wv = threadIdx.x >> 6;
    if ((threadIdx.x & 63) == 0) { red[0][wv] = dot; red[1][wv] = nn; red[2][wv] = tt; }
    __syncthreads();
    if (threadIdx.x == 0) {
        dot = red[0][0] + red[0][1] + red[0][2] + red[0][3];
        nn  = red[1][0] + red[1][1] + red[1][2] + red[1][3];
        tt  = red[2][0] + red[2][1] + red[2][2] + red[2][3];
        float c = dot / sqrtf(nn * tt);
        atomicAdd(&acc[4], c * (1.0f / (float)NROWS));
    }
}

// ---------------- finalize ----------------
__global__ void finalize_kernel(const float* __restrict__ acc, float* __restrict__ out) {
    if (threadIdx.x == 0)
        out[0] = -acc[0] / acc[1] + acc[2] / acc[3] + GAMMA2_ + acc[4];
}

extern "C" void kernel_launch(void* const* d_in, const int* in_sizes, int n_in,
                              void* d_out, int out_size, void* d_ws, size_t ws_size,
                              hipStream_t stream) {
    const float* output_mle = (const float*)d_in[0];
    const float* attn       = (const float*)d_in[1];
    const float* cover      = (const float*)d_in[2];
    const int*   trg        = (const int*)d_in[3];
    const int*   dec_mask   = (const int*)d_in[4];
    const int*   dec_len    = (const int*)d_in[5];
    const float* W          = (const float*)d_in[6];
    float* out  = (float*)d_out;
    float* acc  = (float*)d_ws;
    float* pred = acc + WS_PRED_OFF;

    hipMemsetAsync(d_ws, 0, (WS_PRED_OFF + NROWS * D_) * sizeof(float), stream);
    misc_kernel<<<256, 256, 0, stream>>>(output_mle, attn, cover, trg, dec_mask, dec_len, acc);
    gemm_kernel<<<16 * SPLITK, 256, 0, stream>>>(output_mle, W, pred);
    ot_kernel<<<NROWS, 256, 0, stream>>>(pred, W, trg, acc);
    finalize_kernel<<<1, 64, 0, stream>>>(acc, out);
}

// Round 2
// 350.260 us; speedup vs baseline: 1.6564x; 1.6564x over previous
//
#include <hip/hip_runtime.h>
#include <math.h>

#define B_ 4
#define T_ 128
#define V_ 50257
#define D_ 512
#define NROWS 512           // B*T
#define GAMMA2_ 0.1f

#define BK 32
#define KC 800              // k per split chunk (multiple of 32)
#define SPLITK 64           // 64*800 = 51200 >= 50257
#define LDA 40              // As row stride in shorts (32 + 8 pad)
#define LDB 40              // Bs row stride in shorts

typedef __attribute__((ext_vector_type(8))) short s8v;     // 8 bf16 (4 VGPRs)
typedef __attribute__((ext_vector_type(4))) float f4v;     // MFMA C/D

// ws layout (floats): [0]=nll_sum [1]=valid_cnt [2]=cov_sum [3]=declen_sum [4]=ot_sum
// [256 ..] pred[512*512]
#define WS_PRED_OFF 256

__device__ inline unsigned short f2bf(float f) {
    unsigned int u = __float_as_uint(f);
    u += 0x7fffu + ((u >> 16) & 1u);
    return (unsigned short)(u >> 16);
}

__device__ inline float wave_reduce(float v) {
    #pragma unroll
    for (int o = 32; o > 0; o >>= 1) v += __shfl_down(v, o, 64);
    return v;
}

// ---------------- misc: nll, coverage, dec_len sums ----------------
__global__ void misc_kernel(const float* __restrict__ output_mle,
                            const float* __restrict__ attn,
                            const float* __restrict__ cover,
                            const int* __restrict__ trg,
                            const int* __restrict__ dec_mask,
                            const int* __restrict__ dec_len,
                            float* __restrict__ acc) {
    int bid = blockIdx.x;
    if (bid < 64) {
        // coverage: B*LSRC*T = 262144 floats = 65536 float4; 64 blocks x 256 thr x 4 iters
        float s = 0.f;
        const float4* a4 = (const float4*)attn;
        const float4* c4 = (const float4*)cover;
        for (int i4 = bid * 256 + threadIdx.x; i4 < 65536; i4 += 64 * 256) {
            float4 a = a4[i4];
            float4 c = c4[i4];
            int b = i4 >> 14;                 // / 16384 float4 per batch
            int t = (i4 << 2) & (T_ - 1);
            int4 m = *(const int4*)&dec_mask[(b << 7) + t];
            s += m.x ? 0.f : fminf(a.x, c.x);
            s += m.y ? 0.f : fminf(a.y, c.y);
            s += m.z ? 0.f : fminf(a.z, c.z);
            s += m.w ? 0.f : fminf(a.w, c.w);
        }
        s = wave_reduce(s);
        if ((threadIdx.x & 63) == 0) atomicAdd(&acc[2], s);
    } else {
        float lp = 0.f, cnt = 0.f;
        for (int i = threadIdx.x; i < NROWS; i += 256) {
            int tg = trg[i];
            if (tg != 0) {
                lp += __logf(output_mle[(size_t)i * V_ + tg]);
                cnt += 1.f;
            }
        }
        lp = wave_reduce(lp); cnt = wave_reduce(cnt);
        if ((threadIdx.x & 63) == 0) { atomicAdd(&acc[0], lp); atomicAdd(&acc[1], cnt); }
        if (threadIdx.x < B_) atomicAdd(&acc[3], (float)dec_len[threadIdx.x]);
    }
}

// ---------------- GEMM: pred += exp(X) * W  (split-K, bf16 MFMA, reg-prefetch) ----
__launch_bounds__(256)
__global__ void gemm_kernel(const float* __restrict__ X,
                            const float* __restrict__ W,
                            float* __restrict__ pred) {
    __shared__ __align__(16) short As[128 * LDA];
    __shared__ __align__(16) short Bs[128 * LDB];

    const int bx   = blockIdx.x;
    const int tile = bx & 15;
    const int s    = bx >> 4;
    const int i0   = (tile & 3) * 128;    // row block
    const int d0   = (tile >> 2) * 128;   // col block
    const int ks   = s * KC;
    const int ke   = min(ks + KC, V_);
    if (ks >= ke) return;                 // empty tail split

    const int tid  = threadIdx.x;
    const int lane = tid & 63;
    const int wave = tid >> 6;
    const int wm   = (wave & 1) * 64;
    const int wn   = (wave >> 1) * 64;
    const int l15  = lane & 15;
    const int l4   = lane >> 4;

    // staging thread roles
    const int ar   = tid >> 1;            // A row 0..127
    const int akh  = (tid & 1) * 16;      // A k-half offset
    const int bn2  = (tid & 63) * 2;      // B col pair 0..126
    const int bkq  = (tid >> 6) * 8;      // B k-octet

    const float* Abase = X + (size_t)(i0 + ar) * V_;
    const float* Bbase = W + d0 + bn2;

    float4 abuf[4];
    float2 bbuf[8];

    auto load_regs = [&](int k0) {
        #pragma unroll
        for (int q = 0; q < 4; q++) {
            int gk = min(k0 + akh + q * 4, V_ - 4);   // clamp in-bounds, mask later
            abuf[q] = *(const float4*)(Abase + gk);
        }
        #pragma unroll
        for (int j = 0; j < 8; j++) {
            int gk = min(k0 + bkq + j, V_ - 1);
            bbuf[j] = *(const float2*)(Bbase + (size_t)gk * D_);
        }
    };

    f4v acc[4][4];
    #pragma unroll
    for (int a = 0; a < 4; a++)
        #pragma unroll
        for (int b = 0; b < 4; b++) acc[a][b] = (f4v)0.f;

    load_regs(ks);

    for (int k0 = ks; k0 < ke; k0 += BK) {
        __syncthreads();   // LDS free (prev MFMA done)

        // ---- convert A regs -> LDS (waits on this iter's loads)
        {
            s8v lo, hi;
            #pragma unroll
            for (int q = 0; q < 4; q++) {
                #pragma unroll
                for (int e = 0; e < 4; e++) {
                    int gk = k0 + akh + q * 4 + e;
                    float x = ((const float*)&abuf[q])[e];
                    unsigned short b = (gk < ke) ? f2bf(__expf(x)) : (unsigned short)0;
                    int idx = q * 4 + e;
                    if (idx < 8) lo[idx] = (short)b; else hi[idx - 8] = (short)b;
                }
            }
            *(s8v*)&As[ar * LDA + akh]     = lo;
            *(s8v*)&As[ar * LDA + akh + 8] = hi;
        }
        // ---- convert B regs -> LDS (transposed [n][k])
        {
            s8v r0, r1;
            #pragma unroll
            for (int j = 0; j < 8; j++) {
                int gk = k0 + bkq + j;
                bool v = gk < ke;
                r0[j] = (short)(v ? f2bf(bbuf[j].x) : 0);
                r1[j] = (short)(v ? f2bf(bbuf[j].y) : 0);
            }
            *(s8v*)&Bs[bn2 * LDB + bkq]       = r0;
            *(s8v*)&Bs[(bn2 + 1) * LDB + bkq] = r1;
        }

        // ---- prefetch next iter's globals (in flight across MFMA phase)
        if (k0 + BK < ke) load_regs(k0 + BK);

        __syncthreads();   // LDS ready

        s8v af[4], bf[4];
        #pragma unroll
        for (int mi = 0; mi < 4; mi++)
            af[mi] = *(const s8v*)&As[(wm + mi * 16 + l15) * LDA + l4 * 8];
        #pragma unroll
        for (int ni = 0; ni < 4; ni++)
            bf[ni] = *(const s8v*)&Bs[(wn + ni * 16 + l15) * LDB + l4 * 8];
        #pragma unroll
        for (int mi = 0; mi < 4; mi++)
            #pragma unroll
            for (int ni = 0; ni < 4; ni++)
                acc[mi][ni] = __builtin_amdgcn_mfma_f32_16x16x32_bf16(
                    af[mi], bf[ni], acc[mi][ni], 0, 0, 0);
    }

    // ---- epilogue: C/D layout col=lane&15, row=(lane>>4)*4+r
    #pragma unroll
    for (int mi = 0; mi < 4; mi++) {
        #pragma unroll
        for (int ni = 0; ni < 4; ni++) {
            int col = d0 + wn + ni * 16 + l15;
            #pragma unroll
            for (int r = 0; r < 4; r++) {
                int row = i0 + wm + mi * 16 + l4 * 4 + r;
                atomicAdd(&pred[row * D_ + col], acc[mi][ni][r]);
            }
        }
    }
}

// ---------------- ot: mean_i cos(pred_i, W[trg_i]) ----------------
__global__ void ot_kernel(const float* __restrict__ pred,
                          const float* __restrict__ W,
                          const int* __restrict__ trg,
                          float* __restrict__ acc) {
    int wave = threadIdx.x >> 6, lane = threadIdx.x & 63;
    int row  = blockIdx.x * 4 + wave;
    const float4* p = (const float4*)(pred + (size_t)row * D_) + lane * 2;
    const float4* t = (const float4*)(W + (size_t)trg[row] * D_) + lane * 2;
    float dot = 0.f, nn = 0.f, tt = 0.f;
    #pragma unroll
    for (int q = 0; q < 2; q++) {
        float4 pv = p[q], tv = t[q];
        dot += pv.x * tv.x + pv.y * tv.y + pv.z * tv.z + pv.w * tv.w;
        nn  += pv.x * pv.x + pv.y * pv.y + pv.z * pv.z + pv.w * pv.w;
        tt  += tv.x * tv.x + tv.y * tv.y + tv.z * tv.z + tv.w * tv.w;
    }
    dot = wave_reduce(dot); nn = wave_reduce(nn); tt = wave_reduce(tt);
    if (lane == 0)
        atomicAdd(&acc[4], (dot / sqrtf(nn * tt)) * (1.0f / (float)NROWS));
}

// ---------------- finalize ----------------
__global__ void finalize_kernel(const float* __restrict__ acc, float* __restrict__ out) {
    if (threadIdx.x == 0)
        out[0] = -acc[0] / acc[1] + acc[2] / acc[3] + GAMMA2_ + acc[4];
}

extern "C" void kernel_launch(void* const* d_in, const int* in_sizes, int n_in,
                              void* d_out, int out_size, void* d_ws, size_t ws_size,
                              hipStream_t stream) {
    const float* output_mle = (const float*)d_in[0];
    const float* attn       = (const float*)d_in[1];
    const float* cover      = (const float*)d_in[2];
    const int*   trg        = (const int*)d_in[3];
    const int*   dec_mask   = (const int*)d_in[4];
    const int*   dec_len    = (const int*)d_in[5];
    const float* W          = (const float*)d_in[6];
    float* out  = (float*)d_out;
    float* acc  = (float*)d_ws;
    float* pred = acc + WS_PRED_OFF;

    hipMemsetAsync(d_ws, 0, (WS_PRED_OFF + NROWS * D_) * sizeof(float), stream);
    misc_kernel<<<65, 256, 0, stream>>>(output_mle, attn, cover, trg, dec_mask, dec_len, acc);
    gemm_kernel<<<16 * SPLITK, 256, 0, stream>>>(output_mle, W, pred);
    ot_kernel<<<NROWS / 4, 256, 0, stream>>>(pred, W, trg, acc);
    finalize_kernel<<<1, 64, 0, stream>>>(acc, out);
}

// Round 3
// 345.149 us; speedup vs baseline: 1.6809x; 1.0148x over previous
//
#include <hip/hip_runtime.h>
#include <math.h>

#define B_ 4
#define T_ 128
#define V_ 50257
#define D_ 512
#define NROWS 512           // B*T
#define GAMMA2_ 0.1f

#define BK 32
#define KC 640              // k per split chunk (multiple of BK)
#define SPLITK 79           // 79*640 = 50560 >= 50257
#define NIT (KC / BK)       // 20 iters in full splits
#define LDA 40              // As row stride in shorts (32 + 8 pad)
#define LDB 40              // Bs row stride in shorts

typedef __attribute__((ext_vector_type(8))) short s8v;     // 8 bf16 (4 VGPRs)
typedef __attribute__((ext_vector_type(4))) float f4v;     // MFMA C/D

// ws layout (floats): [0]=nll_sum [1]=valid_cnt [2]=cov_sum [3]=declen_sum [4]=ot_sum
// [256..] pred[512*512]
#define WS_PRED_OFF 256

__device__ inline unsigned short f2bf(float f) {
    unsigned int u = __float_as_uint(f);
    u += 0x7fffu + ((u >> 16) & 1u);
    return (unsigned short)(u >> 16);
}

// round-to-nearest-even both halves, build packed dword directly
__device__ inline unsigned int pack2bf(float f0, float f1) {
    unsigned int u0 = __float_as_uint(f0);
    unsigned int u1 = __float_as_uint(f1);
    u0 += 0x7fffu + ((u0 >> 16) & 1u);
    u1 += 0x7fffu + ((u1 >> 16) & 1u);
    return (u0 >> 16) | (u1 & 0xffff0000u);
}

__device__ inline float wave_reduce(float v) {
    #pragma unroll
    for (int o = 32; o > 0; o >>= 1) v += __shfl_down(v, o, 64);
    return v;
}

// ---------------- misc: nll, coverage, dec_len sums ----------------
__global__ void misc_kernel(const float* __restrict__ output_mle,
                            const float* __restrict__ attn,
                            const float* __restrict__ cover,
                            const int* __restrict__ trg,
                            const int* __restrict__ dec_mask,
                            const int* __restrict__ dec_len,
                            float* __restrict__ acc) {
    int bid = blockIdx.x;
    if (bid < 64) {
        float s = 0.f;
        const float4* a4 = (const float4*)attn;
        const float4* c4 = (const float4*)cover;
        for (int i4 = bid * 256 + threadIdx.x; i4 < 65536; i4 += 64 * 256) {
            float4 a = a4[i4];
            float4 c = c4[i4];
            int b = i4 >> 14;
            int t = (i4 << 2) & (T_ - 1);
            int4 m = *(const int4*)&dec_mask[(b << 7) + t];
            s += m.x ? 0.f : fminf(a.x, c.x);
            s += m.y ? 0.f : fminf(a.y, c.y);
            s += m.z ? 0.f : fminf(a.z, c.z);
            s += m.w ? 0.f : fminf(a.w, c.w);
        }
        s = wave_reduce(s);
        if ((threadIdx.x & 63) == 0) atomicAdd(&acc[2], s);
    } else {
        float lp = 0.f, cnt = 0.f;
        for (int i = threadIdx.x; i < NROWS; i += 256) {
            int tg = trg[i];
            if (tg != 0) {
                lp += __logf(output_mle[(size_t)i * V_ + tg]);
                cnt += 1.f;
            }
        }
        lp = wave_reduce(lp); cnt = wave_reduce(cnt);
        if ((threadIdx.x & 63) == 0) { atomicAdd(&acc[0], lp); atomicAdd(&acc[1], cnt); }
        if (threadIdx.x < B_) atomicAdd(&acc[3], (float)dec_len[threadIdx.x]);
    }
}

// ---------------- GEMM: pred += exp(X) * W  (split-K, bf16 MFMA) ----------------
// Pipelined: double-buffered load regs, loads issued a full iteration ahead.
__launch_bounds__(256)
__global__ void gemm_kernel(const float* __restrict__ X,
                            const float* __restrict__ W,
                            float* __restrict__ pred) {
    __shared__ __align__(16) short As[128 * LDA];
    __shared__ __align__(16) short Bs[128 * LDB];

    const int bx   = blockIdx.x;
    const int tile = bx & 15;
    const int s    = bx >> 4;
    const int i0   = (tile & 3) * 128;
    const int d0   = (tile >> 2) * 128;
    const int ks   = s * KC;
    const int ke   = min(ks + KC, V_);

    const int tid  = threadIdx.x;
    const int lane = tid & 63;
    const int wave = tid >> 6;
    const int wm   = (wave & 1) * 64;
    const int wn   = (wave >> 1) * 64;
    const int l15  = lane & 15;
    const int l4   = lane >> 4;

    // staging roles
    const int ar   = tid >> 1;            // A row 0..127
    const int akh  = (tid & 1) * 16;      // A k-half (shorts == elements)
    const int bn2  = (tid & 63) * 2;      // B col pair
    const int bkq  = (tid >> 6) * 8;      // B k-octet

    f4v acc[4][4];
    #pragma unroll
    for (int a = 0; a < 4; a++)
        #pragma unroll
        for (int b = 0; b < 4; b++) acc[a][b] = (f4v)0.f;

    auto stageA = [&](const float4 (&ab)[4]) {
        const float* f = (const float*)&ab[0];
        unsigned int au[8];
        #pragma unroll
        for (int p = 0; p < 8; p++)
            au[p] = pack2bf(__expf(f[2 * p]), __expf(f[2 * p + 1]));
        *(uint4*)&As[ar * LDA + akh]     = *(const uint4*)&au[0];
        *(uint4*)&As[ar * LDA + akh + 8] = *(const uint4*)&au[4];
    };
    auto stageB = [&](const float2 (&bb)[8]) {
        unsigned int r0[4], r1[4];
        #pragma unroll
        for (int p = 0; p < 4; p++) {
            r0[p] = pack2bf(bb[2 * p].x, bb[2 * p + 1].x);
            r1[p] = pack2bf(bb[2 * p].y, bb[2 * p + 1].y);
        }
        *(uint4*)&Bs[bn2 * LDB + bkq]       = *(const uint4*)&r0[0];
        *(uint4*)&Bs[(bn2 + 1) * LDB + bkq] = *(const uint4*)&r1[0];
    };
    auto domfma = [&]() {
        s8v af[4], bfr[4];
        #pragma unroll
        for (int mi = 0; mi < 4; mi++)
            af[mi] = *(const s8v*)&As[(wm + mi * 16 + l15) * LDA + l4 * 8];
        #pragma unroll
        for (int ni = 0; ni < 4; ni++)
            bfr[ni] = *(const s8v*)&Bs[(wn + ni * 16 + l15) * LDB + l4 * 8];
        #pragma unroll
        for (int mi = 0; mi < 4; mi++)
            #pragma unroll
            for (int ni = 0; ni < 4; ni++)
                acc[mi][ni] = __builtin_amdgcn_mfma_f32_16x16x32_bf16(
                    af[mi], bfr[ni], acc[mi][ni], 0, 0, 0);
    };
    auto issue = [&](float4 (&ab)[4], float2 (&bb)[8], const float* ap, const float* bp) {
        #pragma unroll
        for (int q = 0; q < 4; q++) ab[q] = *(const float4*)(ap + q * 4);
        #pragma unroll
        for (int j = 0; j < 8; j++) bb[j] = *(const float2*)(bp + (size_t)j * D_);
    };

    if (ks + KC <= V_) {
        // ---------- full split: clamp-free pipelined loop ----------
        const float* ap = X + (size_t)(i0 + ar) * V_ + ks + akh;
        const float* bp = W + d0 + bn2 + (size_t)(ks + bkq) * D_;
        float4 a0[4], a1[4];
        float2 b0[8], b1[8];
        issue(a0, b0, ap, bp);
        #pragma unroll 1
        for (int it = 0; it < NIT; it += 2) {
            ap += BK; bp += (size_t)BK * D_;
            if (it + 1 < NIT) issue(a1, b1, ap, bp);
            __syncthreads();
            stageA(a0); stageB(b0);
            __syncthreads();
            domfma();

            ap += BK; bp += (size_t)BK * D_;
            if (it + 2 < NIT) issue(a0, b0, ap, bp);
            __syncthreads();
            stageA(a1); stageB(b1);
            __syncthreads();
            domfma();
        }
    } else {
        // ---------- last split: masked single-buffered loop ----------
        const float* Abase = X + (size_t)(i0 + ar) * V_;
        const float* Bbase = W + d0 + bn2;
        for (int k0 = ks; k0 < ke; k0 += BK) {
            float4 ab[4];
            float2 bb[8];
            #pragma unroll
            for (int q = 0; q < 4; q++) {
                int gk = min(k0 + akh + q * 4, V_ - 4);
                ab[q] = *(const float4*)(Abase + gk);
            }
            #pragma unroll
            for (int j = 0; j < 8; j++) {
                int gk = min(k0 + bkq + j, V_ - 1);
                bb[j] = *(const float2*)(Bbase + (size_t)gk * D_);
            }
            __syncthreads();
            {
                unsigned int au[8];
                const float* f = (const float*)&ab[0];
                #pragma unroll
                for (int p = 0; p < 8; p++) {
                    int g0 = k0 + akh + 2 * p;
                    float e0 = (g0     < ke) ? __expf(f[2 * p])     : 0.f;
                    float e1 = (g0 + 1 < ke) ? __expf(f[2 * p + 1]) : 0.f;
                    au[p] = pack2bf(e0, e1);
                }
                *(uint4*)&As[ar * LDA + akh]     = *(const uint4*)&au[0];
                *(uint4*)&As[ar * LDA + akh + 8] = *(const uint4*)&au[4];
            }
            {
                unsigned int r0[4], r1[4];
                #pragma unroll
                for (int p = 0; p < 4; p++) {
                    int g0 = k0 + bkq + 2 * p;
                    float x0 = (g0     < ke) ? bb[2 * p].x     : 0.f;
                    float x1 = (g0 + 1 < ke) ? bb[2 * p + 1].x : 0.f;
                    float y0 = (g0     < ke) ? bb[2 * p].y     : 0.f;
                    float y1 = (g0 + 1 < ke) ? bb[2 * p + 1].y : 0.f;
                    r0[p] = pack2bf(x0, x1);
                    r1[p] = pack2bf(y0, y1);
                }
                *(uint4*)&Bs[bn2 * LDB + bkq]       = *(const uint4*)&r0[0];
                *(uint4*)&Bs[(bn2 + 1) * LDB + bkq] = *(const uint4*)&r1[0];
            }
            __syncthreads();
            domfma();
        }
    }

    // ---- epilogue: C/D layout col=lane&15, row=(lane>>4)*4+r
    #pragma unroll
    for (int mi = 0; mi < 4; mi++) {
        #pragma unroll
        for (int ni = 0; ni < 4; ni++) {
            int col = d0 + wn + ni * 16 + l15;
            #pragma unroll
            for (int r = 0; r < 4; r++) {
                int row = i0 + wm + mi * 16 + l4 * 4 + r;
                atomicAdd(&pred[row * D_ + col], acc[mi][ni][r]);
            }
        }
    }
}

// ---------------- ot: mean_i cos(pred_i, W[trg_i]) ----------------
__global__ void ot_kernel(const float* __restrict__ pred,
                          const float* __restrict__ W,
                          const int* __restrict__ trg,
                          float* __restrict__ acc) {
    int wave = threadIdx.x >> 6, lane = threadIdx.x & 63;
    int row  = blockIdx.x * 4 + wave;
    const float4* p = (const float4*)(pred + (size_t)row * D_) + lane * 2;
    const float4* t = (const float4*)(W + (size_t)trg[row] * D_) + lane * 2;
    float dot = 0.f, nn = 0.f, tt = 0.f;
    #pragma unroll
    for (int q = 0; q < 2; q++) {
        float4 pv = p[q], tv = t[q];
        dot += pv.x * tv.x + pv.y * tv.y + pv.z * tv.z + pv.w * tv.w;
        nn  += pv.x * pv.x + pv.y * pv.y + pv.z * pv.z + pv.w * pv.w;
        tt  += tv.x * tv.x + tv.y * tv.y + tv.z * tv.z + tv.w * tv.w;
    }
    dot = wave_reduce(dot); nn = wave_reduce(nn); tt = wave_reduce(tt);
    if (lane == 0)
        atomicAdd(&acc[4], (dot / sqrtf(nn * tt)) * (1.0f / (float)NROWS));
}

// ---------------- finalize ----------------
__global__ void finalize_kernel(const float* __restrict__ acc, float* __restrict__ out) {
    if (threadIdx.x == 0)
        out[0] = -acc[0] / acc[1] + acc[2] / acc[3] + GAMMA2_ + acc[4];
}

extern "C" void kernel_launch(void* const* d_in, const int* in_sizes, int n_in,
                              void* d_out, int out_size, void* d_ws, size_t ws_size,
                              hipStream_t stream) {
    const float* output_mle = (const float*)d_in[0];
    const float* attn       = (const float*)d_in[1];
    const float* cover      = (const float*)d_in[2];
    const int*   trg        = (const int*)d_in[3];
    const int*   dec_mask   = (const int*)d_in[4];
    const int*   dec_len    = (const int*)d_in[5];
    const float* W          = (const float*)d_in[6];
    float* out  = (float*)d_out;
    float* acc  = (float*)d_ws;
    float* pred = acc + WS_PRED_OFF;

    hipMemsetAsync(d_ws, 0, (WS_PRED_OFF + NROWS * D_) * sizeof(float), stream);
    misc_kernel<<<65, 256, 0, stream>>>(output_mle, attn, cover, trg, dec_mask, dec_len, acc);
    gemm_kernel<<<16 * SPLITK, 256, 0, stream>>>(output_mle, W, pred);
    ot_kernel<<<NROWS / 4, 256, 0, stream>>>(pred, W, trg, acc);
    finalize_kernel<<<1, 64, 0, stream>>>(acc, out);
}

// Round 4
// 322.955 us; speedup vs baseline: 1.7965x; 1.0687x over previous
//
#include <hip/hip_runtime.h>
#include <math.h>

#define B_ 4
#define T_ 128
#define V_ 50257
#define D_ 512
#define NROWS 512           // B*T
#define GAMMA2_ 0.1f

#define BK 32
#define KC 1600             // k per split (multiple of BK)
#define SPLITK 32           // 32*1600 = 51200 >= 50257
#define NIT (KC / BK)       // 50 iters in full splits
#define LDA 40              // As row stride in shorts (32 + 8 pad)
#define LDB 40              // Bs row stride in shorts

#define SLICE (NROWS * D_)  // 262144 floats = 1 MB per split slice

typedef __attribute__((ext_vector_type(8))) short s8v;     // 8 bf16 (4 VGPRs)
typedef __attribute__((ext_vector_type(4))) float f4v;     // MFMA C/D

// ws layout (floats): [0..4]=acc sums, [1024..] partial slices (or pred in fallback)
#define WS_PART_OFF 1024

__device__ inline unsigned int pack2bf(float f0, float f1) {
    unsigned int u0 = __float_as_uint(f0);
    unsigned int u1 = __float_as_uint(f1);
    u0 += 0x7fffu + ((u0 >> 16) & 1u);
    u1 += 0x7fffu + ((u1 >> 16) & 1u);
    return (u0 >> 16) | (u1 & 0xffff0000u);
}

__device__ inline float wave_reduce(float v) {
    #pragma unroll
    for (int o = 32; o > 0; o >>= 1) v += __shfl_down(v, o, 64);
    return v;
}

// ---------------- misc: nll, coverage, dec_len sums ----------------
__global__ void misc_kernel(const float* __restrict__ output_mle,
                            const float* __restrict__ attn,
                            const float* __restrict__ cover,
                            const int* __restrict__ trg,
                            const int* __restrict__ dec_mask,
                            const int* __restrict__ dec_len,
                            float* __restrict__ acc) {
    int bid = blockIdx.x;
    if (bid < 64) {
        float s = 0.f;
        const float4* a4 = (const float4*)attn;
        const float4* c4 = (const float4*)cover;
        for (int i4 = bid * 256 + threadIdx.x; i4 < 65536; i4 += 64 * 256) {
            float4 a = a4[i4];
            float4 c = c4[i4];
            int b = i4 >> 14;
            int t = (i4 << 2) & (T_ - 1);
            int4 m = *(const int4*)&dec_mask[(b << 7) + t];
            s += m.x ? 0.f : fminf(a.x, c.x);
            s += m.y ? 0.f : fminf(a.y, c.y);
            s += m.z ? 0.f : fminf(a.z, c.z);
            s += m.w ? 0.f : fminf(a.w, c.w);
        }
        s = wave_reduce(s);
        if ((threadIdx.x & 63) == 0) atomicAdd(&acc[2], s);
    } else {
        float lp = 0.f, cnt = 0.f;
        for (int i = threadIdx.x; i < NROWS; i += 256) {
            int tg = trg[i];
            if (tg != 0) {
                lp += __logf(output_mle[(size_t)i * V_ + tg]);
                cnt += 1.f;
            }
        }
        lp = wave_reduce(lp); cnt = wave_reduce(cnt);
        if ((threadIdx.x & 63) == 0) { atomicAdd(&acc[0], lp); atomicAdd(&acc[1], cnt); }
        if (threadIdx.x < B_) atomicAdd(&acc[3], (float)dec_len[threadIdx.x]);
    }
}

// ---------------- GEMM: part[s] = exp(X)*W over split s (bf16 MFMA, no atomics) ----
__launch_bounds__(256)
__global__ void gemm_kernel(const float* __restrict__ X,
                            const float* __restrict__ W,
                            float* __restrict__ part,
                            int use_atomic) {
    __shared__ __align__(16) short As[128 * LDA];
    __shared__ __align__(16) short Bs[128 * LDB];

    const int bx   = blockIdx.x;
    const int tile = bx & 15;
    const int s    = bx >> 4;
    const int i0   = (tile & 3) * 128;
    const int d0   = (tile >> 2) * 128;
    const int ks   = s * KC;
    const int ke   = min(ks + KC, V_);

    const int tid  = threadIdx.x;
    const int lane = tid & 63;
    const int wave = tid >> 6;
    const int wm   = (wave & 1) * 64;
    const int wn   = (wave >> 1) * 64;
    const int l15  = lane & 15;
    const int l4   = lane >> 4;

    const int ar   = tid >> 1;            // A row 0..127
    const int akh  = (tid & 1) * 16;      // A k-half
    const int bn2  = (tid & 63) * 2;      // B col pair
    const int bkq  = (tid >> 6) * 8;      // B k-octet

    f4v acc[4][4];
    #pragma unroll
    for (int a = 0; a < 4; a++)
        #pragma unroll
        for (int b = 0; b < 4; b++) acc[a][b] = (f4v)0.f;

    auto stageA = [&](const float4 (&ab)[4]) {
        const float* f = (const float*)&ab[0];
        unsigned int au[8];
        #pragma unroll
        for (int p = 0; p < 8; p++)
            au[p] = pack2bf(__expf(f[2 * p]), __expf(f[2 * p + 1]));
        *(uint4*)&As[ar * LDA + akh]     = *(const uint4*)&au[0];
        *(uint4*)&As[ar * LDA + akh + 8] = *(const uint4*)&au[4];
    };
    auto stageB = [&](const float2 (&bb)[8]) {
        unsigned int r0[4], r1[4];
        #pragma unroll
        for (int p = 0; p < 4; p++) {
            r0[p] = pack2bf(bb[2 * p].x, bb[2 * p + 1].x);
            r1[p] = pack2bf(bb[2 * p].y, bb[2 * p + 1].y);
        }
        *(uint4*)&Bs[bn2 * LDB + bkq]       = *(const uint4*)&r0[0];
        *(uint4*)&Bs[(bn2 + 1) * LDB + bkq] = *(const uint4*)&r1[0];
    };
    auto domfma = [&]() {
        s8v af[4], bfr[4];
        #pragma unroll
        for (int mi = 0; mi < 4; mi++)
            af[mi] = *(const s8v*)&As[(wm + mi * 16 + l15) * LDA + l4 * 8];
        #pragma unroll
        for (int ni = 0; ni < 4; ni++)
            bfr[ni] = *(const s8v*)&Bs[(wn + ni * 16 + l15) * LDB + l4 * 8];
        #pragma unroll
        for (int mi = 0; mi < 4; mi++)
            #pragma unroll
            for (int ni = 0; ni < 4; ni++)
                acc[mi][ni] = __builtin_amdgcn_mfma_f32_16x16x32_bf16(
                    af[mi], bfr[ni], acc[mi][ni], 0, 0, 0);
    };
    auto issue = [&](float4 (&ab)[4], float2 (&bb)[8], const float* ap, const float* bp) {
        #pragma unroll
        for (int q = 0; q < 4; q++) ab[q] = *(const float4*)(ap + q * 4);
        #pragma unroll
        for (int j = 0; j < 8; j++) bb[j] = *(const float2*)(bp + (size_t)j * D_);
    };

    if (ks + KC <= V_) {
        // full split: clamp-free pipelined loop
        const float* ap = X + (size_t)(i0 + ar) * V_ + ks + akh;
        const float* bp = W + d0 + bn2 + (size_t)(ks + bkq) * D_;
        float4 a0[4], a1[4];
        float2 b0[8], b1[8];
        issue(a0, b0, ap, bp);
        #pragma unroll 1
        for (int it = 0; it < NIT; it += 2) {
            ap += BK; bp += (size_t)BK * D_;
            if (it + 1 < NIT) issue(a1, b1, ap, bp);
            __syncthreads();
            stageA(a0); stageB(b0);
            __syncthreads();
            domfma();

            ap += BK; bp += (size_t)BK * D_;
            if (it + 2 < NIT) issue(a0, b0, ap, bp);
            __syncthreads();
            stageA(a1); stageB(b1);
            __syncthreads();
            domfma();
        }
    } else {
        // last split: masked single-buffered loop
        const float* Abase = X + (size_t)(i0 + ar) * V_;
        const float* Bbase = W + d0 + bn2;
        for (int k0 = ks; k0 < ke; k0 += BK) {
            float4 ab[4];
            float2 bb[8];
            #pragma unroll
            for (int q = 0; q < 4; q++) {
                int gk = min(k0 + akh + q * 4, V_ - 4);
                ab[q] = *(const float4*)(Abase + gk);
            }
            #pragma unroll
            for (int j = 0; j < 8; j++) {
                int gk = min(k0 + bkq + j, V_ - 1);
                bb[j] = *(const float2*)(Bbase + (size_t)gk * D_);
            }
            __syncthreads();
            {
                unsigned int au[8];
                const float* f = (const float*)&ab[0];
                #pragma unroll
                for (int p = 0; p < 8; p++) {
                    int g0 = k0 + akh + 2 * p;
                    float e0 = (g0     < ke) ? __expf(f[2 * p])     : 0.f;
                    float e1 = (g0 + 1 < ke) ? __expf(f[2 * p + 1]) : 0.f;
                    au[p] = pack2bf(e0, e1);
                }
                *(uint4*)&As[ar * LDA + akh]     = *(const uint4*)&au[0];
                *(uint4*)&As[ar * LDA + akh + 8] = *(const uint4*)&au[4];
            }
            {
                unsigned int r0[4], r1[4];
                #pragma unroll
                for (int p = 0; p < 4; p++) {
                    int g0 = k0 + bkq + 2 * p;
                    float x0 = (g0     < ke) ? bb[2 * p].x     : 0.f;
                    float x1 = (g0 + 1 < ke) ? bb[2 * p + 1].x : 0.f;
                    float y0 = (g0     < ke) ? bb[2 * p].y     : 0.f;
                    float y1 = (g0 + 1 < ke) ? bb[2 * p + 1].y : 0.f;
                    r0[p] = pack2bf(x0, x1);
                    r1[p] = pack2bf(y0, y1);
                }
                *(uint4*)&Bs[bn2 * LDB + bkq]       = *(const uint4*)&r0[0];
                *(uint4*)&Bs[(bn2 + 1) * LDB + bkq] = *(const uint4*)&r1[0];
            }
            __syncthreads();
            domfma();
        }
    }

    // epilogue: C/D layout col=lane&15, row=(lane>>4)*4+r
    float* dst = part + (use_atomic ? 0 : (size_t)s * SLICE);
    #pragma unroll
    for (int mi = 0; mi < 4; mi++) {
        #pragma unroll
        for (int ni = 0; ni < 4; ni++) {
            int col = d0 + wn + ni * 16 + l15;
            #pragma unroll
            for (int r = 0; r < 4; r++) {
                int row = i0 + wm + mi * 16 + l4 * 4 + r;
                if (use_atomic) atomicAdd(&dst[row * D_ + col], acc[mi][ni][r]);
                else            dst[row * D_ + col] = acc[mi][ni][r];
            }
        }
    }
}

// ---------------- ot: reduce slices + mean_i cos(pred_i, W[trg_i]) ----------------
__global__ void ot_kernel(const float* __restrict__ part,
                          const float* __restrict__ W,
                          const int* __restrict__ trg,
                          float* __restrict__ acc,
                          int nsl) {
    int wave = threadIdx.x >> 6, lane = threadIdx.x & 63;
    int row  = blockIdx.x * 4 + wave;
    const size_t off = (size_t)row * D_ + lane * 8;

    float4 p0 = {0, 0, 0, 0}, p1 = {0, 0, 0, 0};
    for (int s = 0; s < nsl; s++) {
        const float4* ps = (const float4*)(part + (size_t)s * SLICE + off);
        float4 q0 = ps[0], q1 = ps[1];
        p0.x += q0.x; p0.y += q0.y; p0.z += q0.z; p0.w += q0.w;
        p1.x += q1.x; p1.y += q1.y; p1.z += q1.z; p1.w += q1.w;
    }
    const float4* t4 = (const float4*)(W + (size_t)trg[row] * D_ + lane * 8);
    float4 t0 = t4[0], t1 = t4[1];

    float dot = p0.x * t0.x + p0.y * t0.y + p0.z * t0.z + p0.w * t0.w
              + p1.x * t1.x + p1.y * t1.y + p1.z * t1.z + p1.w * t1.w;
    float nn  = p0.x * p0.x + p0.y * p0.y + p0.z * p0.z + p0.w * p0.w
              + p1.x * p1.x + p1.y * p1.y + p1.z * p1.z + p1.w * p1.w;
    float tt  = t0.x * t0.x + t0.y * t0.y + t0.z * t0.z + t0.w * t0.w
              + t1.x * t1.x + t1.y * t1.y + t1.z * t1.z + t1.w * t1.w;

    dot = wave_reduce(dot); nn = wave_reduce(nn); tt = wave_reduce(tt);
    if (lane == 0)
        atomicAdd(&acc[4], (dot / sqrtf(nn * tt)) * (1.0f / (float)NROWS));
}

// ---------------- finalize ----------------
__global__ void finalize_kernel(const float* __restrict__ acc, float* __restrict__ out) {
    if (threadIdx.x == 0)
        out[0] = -acc[0] / acc[1] + acc[2] / acc[3] + GAMMA2_ + acc[4];
}

extern "C" void kernel_launch(void* const* d_in, const int* in_sizes, int n_in,
                              void* d_out, int out_size, void* d_ws, size_t ws_size,
                              hipStream_t stream) {
    const float* output_mle = (const float*)d_in[0];
    const float* attn       = (const float*)d_in[1];
    const float* cover      = (const float*)d_in[2];
    const int*   trg        = (const int*)d_in[3];
    const int*   dec_mask   = (const int*)d_in[4];
    const int*   dec_len    = (const int*)d_in[5];
    const float* W          = (const float*)d_in[6];
    float* out  = (float*)d_out;
    float* acc  = (float*)d_ws;
    float* part = acc + WS_PART_OFF;

    const size_t need = (size_t)WS_PART_OFF * 4 + (size_t)SPLITK * SLICE * 4;
    const bool partial = (ws_size >= need);   // constant across calls: graph-safe

    if (partial) {
        hipMemsetAsync(d_ws, 0, WS_PART_OFF * sizeof(float), stream);
    } else {
        hipMemsetAsync(d_ws, 0, (WS_PART_OFF + SLICE) * sizeof(float), stream);
    }
    misc_kernel<<<65, 256, 0, stream>>>(output_mle, attn, cover, trg, dec_mask, dec_len, acc);
    gemm_kernel<<<16 * SPLITK, 256, 0, stream>>>(output_mle, W, part, partial ? 0 : 1);
    ot_kernel<<<NROWS / 4, 256, 0, stream>>>(part, W, trg, acc, partial ? SPLITK : 1);
    finalize_kernel<<<1, 64, 0, stream>>>(acc, out);
}

// Round 5
// 322.689 us; speedup vs baseline: 1.7979x; 1.0008x over previous
//
#include <hip/hip_runtime.h>
#include <math.h>

#define B_ 4
#define T_ 128
#define V_ 50257
#define D_ 512
#define NROWS 512           // B*T
#define GAMMA2_ 0.1f

#define BK 32
#define KC 1600             // k per split (multiple of BK)
#define SPLITK 32           // 32*1600 = 51200 >= 50257
#define NIT (KC / BK)       // 50 iters in full splits
#define LDA 40              // As row stride in shorts (32 + 8 pad)
#define LDB 40              // Bs row stride in shorts

#define SLICE (NROWS * D_)  // 262144 floats = 1 MB per split slice

typedef __attribute__((ext_vector_type(8))) short s8v;     // 8 bf16 (4 VGPRs)
typedef __attribute__((ext_vector_type(4))) float f4v;     // MFMA C/D

// ws layout (floats): [0..4]=acc sums, [1024..] partial slices (or pred in fallback)
#define WS_PART_OFF 1024

__device__ inline unsigned int pack2bf(float f0, float f1) {
    unsigned int u0 = __float_as_uint(f0);
    unsigned int u1 = __float_as_uint(f1);
    u0 += 0x7fffu + ((u0 >> 16) & 1u);
    u1 += 0x7fffu + ((u1 >> 16) & 1u);
    return (u0 >> 16) | (u1 & 0xffff0000u);
}

// LDS-only barrier: waits lgkmcnt(0), leaves vmcnt (global prefetch) in flight.
// Encoding: vmcnt=63 (bits[3:0]=0xF, [15:14]=3), expcnt=7 ([6:4]), lgkmcnt=0 ([11:8]).
__device__ inline void sync_lds() {
    __builtin_amdgcn_s_waitcnt(0xC07F);
    __builtin_amdgcn_s_barrier();
}

__device__ inline float wave_reduce(float v) {
    #pragma unroll
    for (int o = 32; o > 0; o >>= 1) v += __shfl_down(v, o, 64);
    return v;
}

// ---------------- misc: nll, coverage, dec_len sums ----------------
__global__ void misc_kernel(const float* __restrict__ output_mle,
                            const float* __restrict__ attn,
                            const float* __restrict__ cover,
                            const int* __restrict__ trg,
                            const int* __restrict__ dec_mask,
                            const int* __restrict__ dec_len,
                            float* __restrict__ acc) {
    int bid = blockIdx.x;
    if (bid < 64) {
        float s = 0.f;
        const float4* a4 = (const float4*)attn;
        const float4* c4 = (const float4*)cover;
        for (int i4 = bid * 256 + threadIdx.x; i4 < 65536; i4 += 64 * 256) {
            float4 a = a4[i4];
            float4 c = c4[i4];
            int b = i4 >> 14;
            int t = (i4 << 2) & (T_ - 1);
            int4 m = *(const int4*)&dec_mask[(b << 7) + t];
            s += m.x ? 0.f : fminf(a.x, c.x);
            s += m.y ? 0.f : fminf(a.y, c.y);
            s += m.z ? 0.f : fminf(a.z, c.z);
            s += m.w ? 0.f : fminf(a.w, c.w);
        }
        s = wave_reduce(s);
        if ((threadIdx.x & 63) == 0) atomicAdd(&acc[2], s);
    } else {
        float lp = 0.f, cnt = 0.f;
        for (int i = threadIdx.x; i < NROWS; i += 256) {
            int tg = trg[i];
            if (tg != 0) {
                lp += __logf(output_mle[(size_t)i * V_ + tg]);
                cnt += 1.f;
            }
        }
        lp = wave_reduce(lp); cnt = wave_reduce(cnt);
        if ((threadIdx.x & 63) == 0) { atomicAdd(&acc[0], lp); atomicAdd(&acc[1], cnt); }
        if (threadIdx.x < B_) atomicAdd(&acc[3], (float)dec_len[threadIdx.x]);
    }
}

// ---------------- GEMM: part[s] = exp(X)*W over split s (bf16 MFMA, no atomics) ----
__launch_bounds__(256)
__global__ void gemm_kernel(const float* __restrict__ X,
                            const float* __restrict__ W,
                            float* __restrict__ part,
                            int use_atomic) {
    __shared__ __align__(16) short As[128 * LDA];
    __shared__ __align__(16) short Bs[128 * LDB];

    const int bx   = blockIdx.x;
    const int tile = bx & 15;
    const int s    = bx >> 4;
    const int i0   = (tile & 3) * 128;
    const int d0   = (tile >> 2) * 128;
    const int ks   = s * KC;
    const int ke   = min(ks + KC, V_);

    const int tid  = threadIdx.x;
    const int lane = tid & 63;
    const int wave = tid >> 6;
    const int wm   = (wave & 1) * 64;
    const int wn   = (wave >> 1) * 64;
    const int l15  = lane & 15;
    const int l4   = lane >> 4;

    const int ar   = tid >> 1;            // A row 0..127
    const int akh  = (tid & 1) * 16;      // A k-half
    const int bn2  = (tid & 63) * 2;      // B col pair
    const int bkq  = (tid >> 6) * 8;      // B k-octet

    f4v acc[4][4];
    #pragma unroll
    for (int a = 0; a < 4; a++)
        #pragma unroll
        for (int b = 0; b < 4; b++) acc[a][b] = (f4v)0.f;

    auto stageA = [&](const float4 (&ab)[4]) {
        const float* f = (const float*)&ab[0];
        unsigned int au[8];
        #pragma unroll
        for (int p = 0; p < 8; p++)
            au[p] = pack2bf(__expf(f[2 * p]), __expf(f[2 * p + 1]));
        *(uint4*)&As[ar * LDA + akh]     = *(const uint4*)&au[0];
        *(uint4*)&As[ar * LDA + akh + 8] = *(const uint4*)&au[4];
    };
    auto stageB = [&](const float2 (&bb)[8]) {
        unsigned int r0[4], r1[4];
        #pragma unroll
        for (int p = 0; p < 4; p++) {
            r0[p] = pack2bf(bb[2 * p].x, bb[2 * p + 1].x);
            r1[p] = pack2bf(bb[2 * p].y, bb[2 * p + 1].y);
        }
        *(uint4*)&Bs[bn2 * LDB + bkq]       = *(const uint4*)&r0[0];
        *(uint4*)&Bs[(bn2 + 1) * LDB + bkq] = *(const uint4*)&r1[0];
    };
    auto domfma = [&]() {
        s8v af[4], bfr[4];
        #pragma unroll
        for (int mi = 0; mi < 4; mi++)
            af[mi] = *(const s8v*)&As[(wm + mi * 16 + l15) * LDA + l4 * 8];
        #pragma unroll
        for (int ni = 0; ni < 4; ni++)
            bfr[ni] = *(const s8v*)&Bs[(wn + ni * 16 + l15) * LDB + l4 * 8];
        #pragma unroll
        for (int mi = 0; mi < 4; mi++)
            #pragma unroll
            for (int ni = 0; ni < 4; ni++)
                acc[mi][ni] = __builtin_amdgcn_mfma_f32_16x16x32_bf16(
                    af[mi], bfr[ni], acc[mi][ni], 0, 0, 0);
    };
    auto issue = [&](float4 (&ab)[4], float2 (&bb)[8], const float* ap, const float* bp) {
        #pragma unroll
        for (int q = 0; q < 4; q++) ab[q] = *(const float4*)(ap + q * 4);
        #pragma unroll
        for (int j = 0; j < 8; j++) bb[j] = *(const float2*)(bp + (size_t)j * D_);
    };

    if (ks + KC <= V_) {
        // full split: clamp-free pipelined loop; barriers never drain vmcnt
        const float* ap = X + (size_t)(i0 + ar) * V_ + ks + akh;
        const float* bp = W + d0 + bn2 + (size_t)(ks + bkq) * D_;
        float4 a0[4], a1[4];
        float2 b0[8], b1[8];
        issue(a0, b0, ap, bp);
        #pragma unroll 1
        for (int it = 0; it < NIT; it += 2) {
            ap += BK; bp += (size_t)BK * D_;
            if (it + 1 < NIT) issue(a1, b1, ap, bp);
            sync_lds();
            stageA(a0); stageB(b0);
            sync_lds();
            domfma();

            ap += BK; bp += (size_t)BK * D_;
            if (it + 2 < NIT) issue(a0, b0, ap, bp);
            sync_lds();
            stageA(a1); stageB(b1);
            sync_lds();
            domfma();
        }
    } else {
        // last split: masked single-buffered loop
        const float* Abase = X + (size_t)(i0 + ar) * V_;
        const float* Bbase = W + d0 + bn2;
        for (int k0 = ks; k0 < ke; k0 += BK) {
            float4 ab[4];
            float2 bb[8];
            #pragma unroll
            for (int q = 0; q < 4; q++) {
                int gk = min(k0 + akh + q * 4, V_ - 4);
                ab[q] = *(const float4*)(Abase + gk);
            }
            #pragma unroll
            for (int j = 0; j < 8; j++) {
                int gk = min(k0 + bkq + j, V_ - 1);
                bb[j] = *(const float2*)(Bbase + (size_t)gk * D_);
            }
            sync_lds();
            {
                unsigned int au[8];
                const float* f = (const float*)&ab[0];
                #pragma unroll
                for (int p = 0; p < 8; p++) {
                    int g0 = k0 + akh + 2 * p;
                    float e0 = (g0     < ke) ? __expf(f[2 * p])     : 0.f;
                    float e1 = (g0 + 1 < ke) ? __expf(f[2 * p + 1]) : 0.f;
                    au[p] = pack2bf(e0, e1);
                }
                *(uint4*)&As[ar * LDA + akh]     = *(const uint4*)&au[0];
                *(uint4*)&As[ar * LDA + akh + 8] = *(const uint4*)&au[4];
            }
            {
                unsigned int r0[4], r1[4];
                #pragma unroll
                for (int p = 0; p < 4; p++) {
                    int g0 = k0 + bkq + 2 * p;
                    float x0 = (g0     < ke) ? bb[2 * p].x     : 0.f;
                    float x1 = (g0 + 1 < ke) ? bb[2 * p + 1].x : 0.f;
                    float y0 = (g0     < ke) ? bb[2 * p].y     : 0.f;
                    float y1 = (g0 + 1 < ke) ? bb[2 * p + 1].y : 0.f;
                    r0[p] = pack2bf(x0, x1);
                    r1[p] = pack2bf(y0, y1);
                }
                *(uint4*)&Bs[bn2 * LDB + bkq]       = *(const uint4*)&r0[0];
                *(uint4*)&Bs[(bn2 + 1) * LDB + bkq] = *(const uint4*)&r1[0];
            }
            sync_lds();
            domfma();
        }
    }

    // epilogue: C/D layout col=lane&15, row=(lane>>4)*4+r
    float* dst = part + (use_atomic ? 0 : (size_t)s * SLICE);
    #pragma unroll
    for (int mi = 0; mi < 4; mi++) {
        #pragma unroll
        for (int ni = 0; ni < 4; ni++) {
            int col = d0 + wn + ni * 16 + l15;
            #pragma unroll
            for (int r = 0; r < 4; r++) {
                int row = i0 + wm + mi * 16 + l4 * 4 + r;
                if (use_atomic) atomicAdd(&dst[row * D_ + col], acc[mi][ni][r]);
                else            dst[row * D_ + col] = acc[mi][ni][r];
            }
        }
    }
}

// ---------------- ot: reduce slices + mean_i cos(pred_i, W[trg_i]) ----------------
__global__ void ot_kernel(const float* __restrict__ part,
                          const float* __restrict__ W,
                          const int* __restrict__ trg,
                          float* __restrict__ acc,
                          int nsl) {
    int wave = threadIdx.x >> 6, lane = threadIdx.x & 63;
    int row  = blockIdx.x * 4 + wave;
    const size_t off = (size_t)row * D_ + lane * 8;

    float4 p0 = {0, 0, 0, 0}, p1 = {0, 0, 0, 0};
    for (int s = 0; s < nsl; s++) {
        const float4* ps = (const float4*)(part + (size_t)s * SLICE + off);
        float4 q0 = ps[0], q1 = ps[1];
        p0.x += q0.x; p0.y += q0.y; p0.z += q0.z; p0.w += q0.w;
        p1.x += q1.x; p1.y += q1.y; p1.z += q1.z; p1.w += q1.w;
    }
    const float4* t4 = (const float4*)(W + (size_t)trg[row] * D_ + lane * 8);
    float4 t0 = t4[0], t1 = t4[1];

    float dot = p0.x * t0.x + p0.y * t0.y + p0.z * t0.z + p0.w * t0.w
              + p1.x * t1.x + p1.y * t1.y + p1.z * t1.z + p1.w * t1.w;
    float nn  = p0.x * p0.x + p0.y * p0.y + p0.z * p0.z + p0.w * p0.w
              + p1.x * p1.x + p1.y * p1.y + p1.z * p1.z + p1.w * p1.w;
    float tt  = t0.x * t0.x + t0.y * t0.y + t0.z * t0.z + t0.w * t0.w
              + t1.x * t1.x + t1.y * t1.y + t1.z * t1.z + t1.w * t1.w;

    dot = wave_reduce(dot); nn = wave_reduce(nn); tt = wave_reduce(tt);
    if (lane == 0)
        atomicAdd(&acc[4], (dot / sqrtf(nn * tt)) * (1.0f / (float)NROWS));
}

// ---------------- finalize ----------------
__global__ void finalize_kernel(const float* __restrict__ acc, float* __restrict__ out) {
    if (threadIdx.x == 0)
        out[0] = -acc[0] / acc[1] + acc[2] / acc[3] + GAMMA2_ + acc[4];
}

extern "C" void kernel_launch(void* const* d_in, const int* in_sizes, int n_in,
                              void* d_out, int out_size, void* d_ws, size_t ws_size,
                              hipStream_t stream) {
    const float* output_mle = (const float*)d_in[0];
    const float* attn       = (const float*)d_in[1];
    const float* cover      = (const float*)d_in[2];
    const int*   trg        = (const int*)d_in[3];
    const int*   dec_mask   = (const int*)d_in[4];
    const int*   dec_len    = (const int*)d_in[5];
    const float* W          = (const float*)d_in[6];
    float* out  = (float*)d_out;
    float* acc  = (float*)d_ws;
    float* part = acc + WS_PART_OFF;

    const size_t need = (size_t)WS_PART_OFF * 4 + (size_t)SPLITK * SLICE * 4;
    const bool partial = (ws_size >= need);   // constant across calls: graph-safe

    if (partial) {
        hipMemsetAsync(d_ws, 0, WS_PART_OFF * sizeof(float), stream);
    } else {
        hipMemsetAsync(d_ws, 0, (WS_PART_OFF + SLICE) * sizeof(float), stream);
    }
    misc_kernel<<<65, 256, 0, stream>>>(output_mle, attn, cover, trg, dec_mask, dec_len, acc);
    gemm_kernel<<<16 * SPLITK, 256, 0, stream>>>(output_mle, W, part, partial ? 0 : 1);
    ot_kernel<<<NROWS / 4, 256, 0, stream>>>(part, W, trg, acc, partial ? SPLITK : 1);
    finalize_kernel<<<1, 64, 0, stream>>>(acc, out);
}